// Round 1
// baseline (1065.988 us; speedup 1.0000x reference)
//
#include <hip/hip_runtime.h>
#include <cstdint>
#include <cstddef>

#define N_ROWS 2048
#define D_DIM  1024
#define B_DIM  32
#define S_DIM  512
#define KT     32

// ---------------------------------------------------------------------------
// Preprocess: detect dtype layout of targets (int32 vs int64) and replace_mask
// (bool-1B vs int32 vs float32), normalize into ws as int32. Deterministic.
// ---------------------------------------------------------------------------
__global__ __launch_bounds__(256) void preprocess_kernel(
    const unsigned char* __restrict__ traw,
    const unsigned char* __restrict__ mraw,
    int* __restrict__ tgt32, int* __restrict__ mask32)
{
    __shared__ int fFloat, fByte, fOdd;
    const int tid = threadIdx.x;
    if (tid == 0) { fFloat = 0; fByte = 0; fOdd = 0; }
    __syncthreads();

    // Mask sniff: only first 2048 bytes (safe for smallest possible layout).
    const unsigned int* mw = (const unsigned int*)mraw;
    for (int i = tid; i < 512; i += 256) {
        unsigned int w = mw[i];
        if (w == 0x3f800000u) atomicOr(&fFloat, 1);        // float32 1.0f
        if (w & 0xFFFFFF00u)  atomicOr(&fByte, 1);         // nonzero byte at off%4!=0
    }
    // Target sniff: 2048 int32 words = 8192 B, safe for int32 or int64 buffer.
    const unsigned int* tw = (const unsigned int*)traw;
    for (int i = tid; i < N_ROWS; i += 256) {
        if ((i & 1) && tw[i] != 0u) atomicOr(&fOdd, 1);    // int64 high words are 0
    }
    __syncthreads();
    const int mlayout = fFloat ? 2 : (fByte ? 1 : 0);      // 2=f32, 1=byte, 0=int32
    const int tis64   = fOdd ? 0 : 1;

    for (int i = tid; i < N_ROWS; i += 256) {
        long long t = tis64 ? ((const long long*)traw)[i] : (long long)((const int*)traw)[i];
        tgt32[i] = (int)t;
        int m;
        if (mlayout == 1) m = (mraw[i] != 0);
        else              m = (((const unsigned int*)mraw)[i] != 0u);
        mask32[i] = m;
    }
}

// ---------------------------------------------------------------------------
// Gather final_emb[n] = replace ? cls[b] : lhs[b, tok]
// ---------------------------------------------------------------------------
__global__ __launch_bounds__(256) void gather_kernel(
    const float* __restrict__ lhs, const float* __restrict__ cls,
    const int* __restrict__ bids, const int* __restrict__ toks,
    const int* __restrict__ mask32, float* __restrict__ emb)
{
    const int n = blockIdx.x;
    const int b = bids[n];
    const int tok = toks[n];
    const float* src = mask32[n] ? (cls + (size_t)b * D_DIM)
                                 : (lhs + ((size_t)b * S_DIM + (size_t)tok) * D_DIM);
    float4 v = ((const float4*)src)[threadIdx.x];
    ((float4*)(emb + (size_t)n * D_DIM))[threadIdx.x] = v;
}

// ---------------------------------------------------------------------------
// Fused GEMM: out = A[N x K] @ W[C x K]^T (+bias).
// mode 0: store full result to Hout.
// mode 1: fused epilogue: per-row sum(exp(logit)) -> atomicAdd(sumexp[row]);
//         logit at rel target class -> tgtOut[row];
//         logits at classes specBase/specBase+1 -> spec0/spec1[row].
// Block tile 64 rows x 64 classes, 16x16 threads, 4x4 microtile, K-tile 32.
// LDS is transposed (As[k][row]) with pad 4 -> aligned float4 reads.
// ---------------------------------------------------------------------------
__global__ __launch_bounds__(256) void fused_gemm_kernel(
    const float* __restrict__ A, int K,
    const float* __restrict__ W, int C,
    const float* __restrict__ bias,
    int mode,
    float* __restrict__ Hout,
    float* __restrict__ sumexp,
    float* __restrict__ tgtOut,
    float* __restrict__ spec0, float* __restrict__ spec1, int specBase,
    const int* __restrict__ tgt32, int lo, int relMax,
    int tilesPerChunk)
{
    __shared__ float As[KT][68];
    __shared__ float Ws[KT][68];

    const int tid = threadIdx.x;
    const int tx = tid & 15;       // class group 0..15
    const int ty = tid >> 4;       // row group 0..15
    const int rowBase = blockIdx.x * 64;
    const int ctile0  = blockIdx.y * tilesPerChunk;

    int   rel[4];
    float rowsum[4] = {0.f, 0.f, 0.f, 0.f};
    if (mode == 1) {
        #pragma unroll
        for (int i = 0; i < 4; ++i) {
            int t = tgt32[rowBase + ty * 4 + i] - lo;
            rel[i] = t < 0 ? 0 : (t > relMax ? relMax : t);
        }
    }

    const int lr = tid >> 2;           // 0..63 : row/class index for staging
    const int lk = (tid & 3) * 4;      // 0,4,8,12 : k offset for staging

    for (int ct = 0; ct < tilesPerChunk; ++ct) {
        const int cBase = (ctile0 + ct) * 64;
        if (cBase >= C) break;

        float acc[4][4];
        #pragma unroll
        for (int i = 0; i < 4; ++i)
            #pragma unroll
            for (int j = 0; j < 4; ++j) acc[i][j] = 0.f;

        const float* aRow = A + (size_t)(rowBase + lr) * K;
        const int    wc   = cBase + lr;
        const float* wRow = (wc < C) ? (W + (size_t)wc * K) : nullptr;

        for (int k0 = 0; k0 < K; k0 += KT) {
            float4 a0 = *(const float4*)(aRow + k0 + lk);
            float4 a1 = *(const float4*)(aRow + k0 + 16 + lk);
            float4 w0 = make_float4(0.f, 0.f, 0.f, 0.f);
            float4 w1 = make_float4(0.f, 0.f, 0.f, 0.f);
            if (wRow) {
                w0 = *(const float4*)(wRow + k0 + lk);
                w1 = *(const float4*)(wRow + k0 + 16 + lk);
            }
            __syncthreads();   // previous tile's compute done before overwrite
            As[lk + 0][lr] = a0.x; As[lk + 1][lr] = a0.y;
            As[lk + 2][lr] = a0.z; As[lk + 3][lr] = a0.w;
            As[lk + 16][lr] = a1.x; As[lk + 17][lr] = a1.y;
            As[lk + 18][lr] = a1.z; As[lk + 19][lr] = a1.w;
            Ws[lk + 0][lr] = w0.x; Ws[lk + 1][lr] = w0.y;
            Ws[lk + 2][lr] = w0.z; Ws[lk + 3][lr] = w0.w;
            Ws[lk + 16][lr] = w1.x; Ws[lk + 17][lr] = w1.y;
            Ws[lk + 18][lr] = w1.z; Ws[lk + 19][lr] = w1.w;
            __syncthreads();

            #pragma unroll
            for (int k = 0; k < KT; ++k) {
                float4 a4 = *(const float4*)&As[k][ty * 4];
                float4 w4 = *(const float4*)&Ws[k][tx * 4];
                float av[4] = {a4.x, a4.y, a4.z, a4.w};
                float wv[4] = {w4.x, w4.y, w4.z, w4.w};
                #pragma unroll
                for (int i = 0; i < 4; ++i)
                    #pragma unroll
                    for (int j = 0; j < 4; ++j)
                        acc[i][j] += av[i] * wv[j];
            }
        }

        if (mode == 0) {
            #pragma unroll
            for (int i = 0; i < 4; ++i) {
                const int row = rowBase + ty * 4 + i;
                #pragma unroll
                for (int j = 0; j < 4; ++j) {
                    const int c = cBase + tx * 4 + j;
                    if (c < C) Hout[(size_t)row * C + c] = acc[i][j];
                }
            }
        } else {
            float bj[4];
            #pragma unroll
            for (int j = 0; j < 4; ++j) {
                const int c = cBase + tx * 4 + j;
                bj[j] = (bias != nullptr && c < C) ? bias[c] : 0.f;
            }
            #pragma unroll
            for (int i = 0; i < 4; ++i) {
                const int row = rowBase + ty * 4 + i;
                float s = 0.f;
                #pragma unroll
                for (int j = 0; j < 4; ++j) {
                    const int c = cBase + tx * 4 + j;
                    if (c < C) {
                        const float v = acc[i][j] + bj[j];
                        s += expf(v);
                        if (rel[i] == c) tgtOut[row] = v;
                        if (c == specBase) spec0[row] = v;
                        else if (c == specBase + 1) spec1[row] = v;
                    }
                }
                rowsum[i] += s;
            }
        }
    }

    if (mode == 1) {
        #pragma unroll
        for (int i = 0; i < 4; ++i) {
            float v = rowsum[i];
            #pragma unroll
            for (int m = 1; m < 16; m <<= 1) v += __shfl_xor(v, m);
            if (tx == 0) atomicAdd(&sumexp[rowBase + ty * 4 + i], v);
        }
    }
}

// ---------------------------------------------------------------------------
// Finalize: per-row output + loss = -mean(out). Single block.
// ---------------------------------------------------------------------------
__global__ __launch_bounds__(256) void finalize_kernel(
    const float* __restrict__ seH, const float* __restrict__ se0,
    const float* __restrict__ se1,
    const float* __restrict__ tgtH, const float* __restrict__ tg0,
    const float* __restrict__ tg1,
    const float* __restrict__ c0, const float* __restrict__ c1,
    const int* __restrict__ tgt32,
    float* __restrict__ out)
{
    const int tid = threadIdx.x;
    float lsum = 0.f;
    for (int n = tid; n < N_ROWS; n += 256) {
        const float lseH = logf(seH[n]);
        const int t = tgt32[n];
        float o;
        if (t < 4000)        o = tgtH[n] - lseH;
        else if (t < 20000)  o = (c0[n] - lseH) + tg0[n] - logf(se0[n]);
        else                 o = (c1[n] - lseH) + tg1[n] - logf(se1[n]);
        out[n] = o;
        lsum += o;
    }
    #pragma unroll
    for (int m = 1; m < 64; m <<= 1) lsum += __shfl_xor(lsum, m);
    __shared__ float wsum[4];
    const int wid = tid >> 6;
    if ((tid & 63) == 0) wsum[wid] = lsum;
    __syncthreads();
    if (tid == 0) out[N_ROWS] = -(wsum[0] + wsum[1] + wsum[2] + wsum[3]) / (float)N_ROWS;
}

// ---------------------------------------------------------------------------
extern "C" void kernel_launch(void* const* d_in, const int* in_sizes, int n_in,
                              void* d_out, int out_size, void* d_ws, size_t ws_size,
                              hipStream_t stream)
{
    const unsigned char* traw = (const unsigned char*)d_in[0];
    const float* lhs    = (const float*)d_in[1];
    const float* cls    = (const float*)d_in[2];
    const int*   bids   = (const int*)d_in[3];
    const int*   toks   = (const int*)d_in[4];
    const unsigned char* mraw = (const unsigned char*)d_in[5];
    const float* headW  = (const float*)d_in[6];
    const float* headB  = (const float*)d_in[7];
    const float* t0proj = (const float*)d_in[8];
    const float* t0out  = (const float*)d_in[9];
    const float* t1proj = (const float*)d_in[10];
    const float* t1out  = (const float*)d_in[11];

    char* ws = (char*)d_ws;
    float* emb   = (float*)(ws + 0);          // 2048*1024*4 = 8388608
    float* h0    = (float*)(ws + 8388608);    // 2048*256*4  = 2097152
    float* h1    = (float*)(ws + 10485760);   // 2048*64*4   = 524288
    int*   tgt32 = (int*)  (ws + 11010048);   // 8192
    int*   mask32= (int*)  (ws + 11018240);   // 8192
    float* sums  = (float*)(ws + 11026432);   // 3*8192
    float* seH = sums;
    float* se0 = sums + N_ROWS;
    float* se1 = sums + 2 * N_ROWS;
    float* tgtH  = (float*)(ws + 11051008);
    float* tg0   = (float*)(ws + 11059200);
    float* tg1   = (float*)(ws + 11067392);
    float* c0    = (float*)(ws + 11075584);
    float* c1    = (float*)(ws + 11083776);

    hipMemsetAsync(sums, 0, 3 * N_ROWS * sizeof(float), stream);

    preprocess_kernel<<<1, 256, 0, stream>>>(traw, mraw, tgt32, mask32);
    gather_kernel<<<N_ROWS, 256, 0, stream>>>(lhs, cls, bids, toks, mask32, emb);

    // tail hidden projections (store mode)
    fused_gemm_kernel<<<dim3(32, 1), 256, 0, stream>>>(
        emb, 1024, t0proj, 256, nullptr, 0, h0,
        nullptr, nullptr, nullptr, nullptr, -100, tgt32, 0, 0, 4);
    fused_gemm_kernel<<<dim3(32, 1), 256, 0, stream>>>(
        emb, 1024, t1proj, 64, nullptr, 0, h1,
        nullptr, nullptr, nullptr, nullptr, -100, tgt32, 0, 0, 1);

    // head: C=4002, capture classes 4000/4001 as cluster logits
    fused_gemm_kernel<<<dim3(32, 8), 256, 0, stream>>>(
        emb, 1024, headW, 4002, headB, 1, nullptr,
        seH, tgtH, c0, c1, 4000, tgt32, 0, 3999, 8);

    // tail0 logits: C=16000 -> 250 tiles -> 32 chunks of 8
    fused_gemm_kernel<<<dim3(32, 32), 256, 0, stream>>>(
        h0, 256, t0out, 16000, nullptr, 1, nullptr,
        se0, tg0, nullptr, nullptr, -100, tgt32, 4000, 15999, 8);

    // tail1 logits: C=30000 -> 469 tiles -> 59 chunks of 8
    fused_gemm_kernel<<<dim3(32, 59), 256, 0, stream>>>(
        h1, 64, t1out, 30000, nullptr, 1, nullptr,
        se1, tg1, nullptr, nullptr, -100, tgt32, 20000, 29999, 8);

    finalize_kernel<<<1, 256, 0, stream>>>(seH, se0, se1, tgtH, tg0, tg1,
                                           c0, c1, tgt32, (float*)d_out);
}

// Round 2
// 197.532 us; speedup vs baseline: 5.3965x; 5.3965x over previous
//
#include <hip/hip_runtime.h>
#include <cstdint>
#include <cstddef>

#define N_ROWS 2048
#define D_DIM  1024

typedef __bf16 bf16x8 __attribute__((ext_vector_type(8)));
typedef float  f32x4  __attribute__((ext_vector_type(4)));

__device__ __forceinline__ unsigned short f2bf(float f) {
    unsigned int u = __float_as_uint(f);
    unsigned int r = (u + 0x7fffu + ((u >> 16) & 1u)) >> 16;   // RNE
    return (unsigned short)r;
}
__device__ __forceinline__ float bf2f(unsigned short u) {
    return __uint_as_float(((unsigned int)u) << 16);
}
__device__ __forceinline__ void gload_lds16(const void* g, void* lds) {
    __builtin_amdgcn_global_load_lds(
        (const __attribute__((address_space(1))) unsigned int*)g,
        (__attribute__((address_space(3))) unsigned int*)lds, 16, 0, 0);
}

// ---------------------------------------------------------------------------
// dtype sniffing (targets int32/int64, mask bool/int/float) -> int32 buffers
// ---------------------------------------------------------------------------
__global__ __launch_bounds__(256) void preprocess_kernel(
    const unsigned char* __restrict__ traw,
    const unsigned char* __restrict__ mraw,
    int* __restrict__ tgt32, int* __restrict__ mask32)
{
    __shared__ int fFloat, fByte, fOdd;
    const int tid = threadIdx.x;
    if (tid == 0) { fFloat = 0; fByte = 0; fOdd = 0; }
    __syncthreads();

    const unsigned int* mw = (const unsigned int*)mraw;
    for (int i = tid; i < 512; i += 256) {
        unsigned int w = mw[i];
        if (w == 0x3f800000u) atomicOr(&fFloat, 1);
        if (w & 0xFFFFFF00u)  atomicOr(&fByte, 1);
    }
    const unsigned int* tw = (const unsigned int*)traw;
    for (int i = tid; i < N_ROWS; i += 256) {
        if ((i & 1) && tw[i] != 0u) atomicOr(&fOdd, 1);
    }
    __syncthreads();
    const int mlayout = fFloat ? 2 : (fByte ? 1 : 0);
    const int tis64   = fOdd ? 0 : 1;

    for (int i = tid; i < N_ROWS; i += 256) {
        long long t = tis64 ? ((const long long*)traw)[i] : (long long)((const int*)traw)[i];
        tgt32[i] = (int)t;
        int m;
        if (mlayout == 1) m = (mraw[i] != 0);
        else              m = (((const unsigned int*)mraw)[i] != 0u);
        mask32[i] = m;
    }
}

// ---------------------------------------------------------------------------
// gather + fp32->bf16: emb[n] = replace ? cls[b] : lhs[b,tok]
// ---------------------------------------------------------------------------
__global__ __launch_bounds__(256) void gather_cvt_kernel(
    const float* __restrict__ lhs, const float* __restrict__ cls,
    const int* __restrict__ bids, const int* __restrict__ toks,
    const int* __restrict__ mask32, unsigned short* __restrict__ emb)
{
    const int n = blockIdx.x;
    const int b = bids[n];
    const int tok = toks[n];
    const float* src = mask32[n] ? (cls + (size_t)b * D_DIM)
                                 : (lhs + ((size_t)b * 512 + (size_t)tok) * D_DIM);
    float4 v = ((const float4*)src)[threadIdx.x];
    ushort4 o;
    o.x = f2bf(v.x); o.y = f2bf(v.y); o.z = f2bf(v.z); o.w = f2bf(v.w);
    ((ushort4*)(emb + (size_t)n * D_DIM))[threadIdx.x] = o;
}

// fp32 -> bf16 bulk convert (n multiple of 4)
__global__ __launch_bounds__(256) void cvt_kernel(
    const float* __restrict__ src, unsigned short* __restrict__ dst, int n)
{
    const int i = (blockIdx.x * 256 + threadIdx.x) * 4;
    if (i >= n) return;
    float4 v = *(const float4*)(src + i);
    ushort4 o;
    o.x = f2bf(v.x); o.y = f2bf(v.y); o.z = f2bf(v.z); o.w = f2bf(v.w);
    *(ushort4*)(dst + i) = o;
}

// split h01 fp32 [2048][320] -> h0 bf16 [2048][256], h1 bf16 [2048][64]
__global__ __launch_bounds__(256) void cvt_h01_kernel(
    const float* __restrict__ h01, unsigned short* __restrict__ h0,
    unsigned short* __restrict__ h1)
{
    const int idx = blockIdx.x * 256 + threadIdx.x;
    if (idx >= 2048 * 320) return;
    const int r = idx / 320;
    const int c = idx - r * 320;
    const unsigned short v = f2bf(h01[idx]);
    if (c < 256) h0[r * 256 + c] = v;
    else         h1[r * 64 + (c - 256)] = v;
}

// ---------------------------------------------------------------------------
// bf16 MFMA GEMM: C[row][col] = sum_k A[row][k] * W[col][k]
// BM=BN=128, 4 waves (2x2), each wave 64x64 via 4x4 frags of 16x16x32.
// MODE 1: fused sum(exp(logit+bias)) -> atomicAdd(sumexp[row]); chunked cols.
// MODE 2: split-K, atomicAdd fp32 into outF (grid.z = K chunks of kLen).
// LDS XOR swizzle: 16B slot s at row r stored at s ^ ((r>>1)&3).
// ---------------------------------------------------------------------------
template<int MODE>
__global__ __launch_bounds__(256) void gemm_kernel(
    const unsigned short* __restrict__ A, int K,
    const unsigned short* __restrict__ W, int C,
    const float* __restrict__ bias,
    float* __restrict__ outF,
    float* __restrict__ sumexp,
    int colTiles, int kOff, int kLen)
{
    __shared__ char lds[16384];
    char* As = lds;
    char* Ws = lds + 8192;

    const int tid = threadIdx.x;
    const int w  = tid >> 6;
    const int l  = tid & 63;
    const int wr = w >> 1, wc = w & 1;
    const int q  = l >> 4, r16 = l & 15;
    const int rowA0 = blockIdx.x * 128;
    const int kBeg  = kOff + blockIdx.z * kLen;

    const int sR = (w << 5) + (l >> 2);   // staging row (+ it*16)
    const int sS = l & 3;                 // staging linear slot

    float esum[4][4];
    if (MODE == 1) {
        #pragma unroll
        for (int m = 0; m < 4; ++m)
            #pragma unroll
            for (int r = 0; r < 4; ++r) esum[m][r] = 0.f;
    }

    for (int ct = 0; ct < colTiles; ++ct) {
        const int cBase = (blockIdx.y * colTiles + ct) * 128;
        if (cBase >= C) break;

        f32x4 acc[4][4];
        #pragma unroll
        for (int m = 0; m < 4; ++m)
            #pragma unroll
            for (int n = 0; n < 4; ++n) acc[m][n] = (f32x4){0.f, 0.f, 0.f, 0.f};

        for (int k0 = kBeg; k0 < kBeg + kLen; k0 += 32) {
            __syncthreads();
            #pragma unroll
            for (int it = 0; it < 2; ++it) {
                const int R  = sR + (it << 4);
                const int Sp = sS ^ ((R >> 1) & 3);
                gload_lds16(A + (size_t)(rowA0 + R) * K + k0 + Sp * 8,
                            As + (w << 11) + (it << 10));
                int Rw = cBase + R; if (Rw >= C) Rw = C - 1;
                gload_lds16(W + (size_t)Rw * K + k0 + Sp * 8,
                            Ws + (w << 11) + (it << 10));
            }
            __syncthreads();

            bf16x8 af[4], bfr[4];
            #pragma unroll
            for (int m = 0; m < 4; ++m) {
                const int row = (wr << 6) + (m << 4) + r16;
                af[m] = *reinterpret_cast<const bf16x8*>(
                    As + row * 64 + ((q ^ ((row >> 1) & 3)) << 4));
            }
            #pragma unroll
            for (int n = 0; n < 4; ++n) {
                const int row = (wc << 6) + (n << 4) + r16;
                bfr[n] = *reinterpret_cast<const bf16x8*>(
                    Ws + row * 64 + ((q ^ ((row >> 1) & 3)) << 4));
            }
            #pragma unroll
            for (int m = 0; m < 4; ++m)
                #pragma unroll
                for (int n = 0; n < 4; ++n)
                    acc[m][n] = __builtin_amdgcn_mfma_f32_16x16x32_bf16(
                        af[m], bfr[n], acc[m][n], 0, 0, 0);
        }

        if (MODE == 2) {
            #pragma unroll
            for (int n = 0; n < 4; ++n) {
                const int c = cBase + (wc << 6) + (n << 4) + r16;
                if (c < C) {
                    #pragma unroll
                    for (int m = 0; m < 4; ++m)
                        #pragma unroll
                        for (int r = 0; r < 4; ++r) {
                            const int row = rowA0 + (wr << 6) + (m << 4) + (q << 2) + r;
                            atomicAdd(&outF[(size_t)row * C + c], acc[m][n][r]);
                        }
                }
            }
        } else {
            float bj[4]; bool vj[4];
            #pragma unroll
            for (int n = 0; n < 4; ++n) {
                const int c = cBase + (wc << 6) + (n << 4) + r16;
                vj[n] = (c < C);
                bj[n] = (vj[n] && bias) ? bias[c] : 0.f;
            }
            #pragma unroll
            for (int m = 0; m < 4; ++m)
                #pragma unroll
                for (int r = 0; r < 4; ++r) {
                    float s = 0.f;
                    #pragma unroll
                    for (int n = 0; n < 4; ++n)
                        if (vj[n]) s += __expf(acc[m][n][r] + bj[n]);
                    esum[m][r] += s;
                }
        }
    }

    if (MODE == 1) {
        #pragma unroll
        for (int m = 0; m < 4; ++m)
            #pragma unroll
            for (int r = 0; r < 4; ++r) {
                float v = esum[m][r];
                v += __shfl_xor(v, 1); v += __shfl_xor(v, 2);
                v += __shfl_xor(v, 4); v += __shfl_xor(v, 8);
                if (r16 == 0)
                    atomicAdd(&sumexp[rowA0 + (wr << 6) + (m << 4) + (q << 2) + r], v);
            }
    }
}

// ---------------------------------------------------------------------------
// per-row target / cluster logit dots (one wave per row)
// ---------------------------------------------------------------------------
__global__ __launch_bounds__(256) void dot_kernel(
    const unsigned short* __restrict__ emb,
    const unsigned short* __restrict__ headW,
    const float* __restrict__ headB,
    const unsigned short* __restrict__ h0,
    const unsigned short* __restrict__ t0out,
    const unsigned short* __restrict__ h1,
    const unsigned short* __restrict__ t1out,
    const int* __restrict__ tgt32,
    float* __restrict__ tgtH, float* __restrict__ c0, float* __restrict__ c1,
    float* __restrict__ tg0, float* __restrict__ tg1)
{
    const int n = blockIdx.x * 4 + (threadIdx.x >> 6);
    const int l = threadIdx.x & 63;
    const int t = tgt32[n];

    const unsigned short* e  = emb + (size_t)n * 1024;
    const int hrow = (t < 4000) ? t : 0;
    const unsigned short* wt = headW + (size_t)hrow * 1024;
    const unsigned short* w0 = headW + (size_t)4000 * 1024;
    const unsigned short* w1 = headW + (size_t)4001 * 1024;

    float st = 0.f, s0 = 0.f, s1 = 0.f;
    for (int i = l; i < 1024; i += 64) {
        const float ev = bf2f(e[i]);
        st += ev * bf2f(wt[i]);
        s0 += ev * bf2f(w0[i]);
        s1 += ev * bf2f(w1[i]);
    }
    float stail = 0.f;
    if (t >= 4000 && t < 20000) {
        const unsigned short* h  = h0 + (size_t)n * 256;
        const unsigned short* ww = t0out + (size_t)(t - 4000) * 256;
        for (int i = l; i < 256; i += 64) stail += bf2f(h[i]) * bf2f(ww[i]);
    } else if (t >= 20000) {
        const unsigned short* h  = h1 + (size_t)n * 64;
        const unsigned short* ww = t1out + (size_t)(t - 20000) * 64;
        stail = bf2f(h[l]) * bf2f(ww[l]);
    }
    #pragma unroll
    for (int msk = 1; msk < 64; msk <<= 1) {
        st    += __shfl_xor(st, msk);
        s0    += __shfl_xor(s0, msk);
        s1    += __shfl_xor(s1, msk);
        stail += __shfl_xor(stail, msk);
    }
    if (l == 0) {
        c0[n] = s0 + headB[4000];
        c1[n] = s1 + headB[4001];
        if (t < 4000)       tgtH[n] = st + headB[t];
        else if (t < 20000) tg0[n]  = stail;
        else                tg1[n]  = stail;
    }
}

// ---------------------------------------------------------------------------
__global__ __launch_bounds__(256) void finalize_kernel(
    const float* __restrict__ seH, const float* __restrict__ se0,
    const float* __restrict__ se1,
    const float* __restrict__ tgtH, const float* __restrict__ tg0,
    const float* __restrict__ tg1,
    const float* __restrict__ c0, const float* __restrict__ c1,
    const int* __restrict__ tgt32,
    float* __restrict__ out)
{
    const int tid = threadIdx.x;
    float lsum = 0.f;
    for (int n = tid; n < N_ROWS; n += 256) {
        const float lseH = logf(seH[n]);
        const int t = tgt32[n];
        float o;
        if (t < 4000)        o = tgtH[n] - lseH;
        else if (t < 20000)  o = (c0[n] - lseH) + tg0[n] - logf(se0[n]);
        else                 o = (c1[n] - lseH) + tg1[n] - logf(se1[n]);
        out[n] = o;
        lsum += o;
    }
    #pragma unroll
    for (int m = 1; m < 64; m <<= 1) lsum += __shfl_xor(lsum, m);
    __shared__ float wsum[4];
    const int wid = tid >> 6;
    if ((tid & 63) == 0) wsum[wid] = lsum;
    __syncthreads();
    if (tid == 0) out[N_ROWS] = -(wsum[0] + wsum[1] + wsum[2] + wsum[3]) / (float)N_ROWS;
}

// ---------------------------------------------------------------------------
extern "C" void kernel_launch(void* const* d_in, const int* in_sizes, int n_in,
                              void* d_out, int out_size, void* d_ws, size_t ws_size,
                              hipStream_t stream)
{
    const unsigned char* traw = (const unsigned char*)d_in[0];
    const float* lhs    = (const float*)d_in[1];
    const float* cls    = (const float*)d_in[2];
    const int*   bids   = (const int*)d_in[3];
    const int*   toks   = (const int*)d_in[4];
    const unsigned char* mraw = (const unsigned char*)d_in[5];
    const float* headW  = (const float*)d_in[6];
    const float* headB  = (const float*)d_in[7];
    const float* t0proj = (const float*)d_in[8];
    const float* t0out  = (const float*)d_in[9];
    const float* t1proj = (const float*)d_in[10];
    const float* t1out  = (const float*)d_in[11];

    char* ws = (char*)d_ws;
    unsigned short* emb_bf    = (unsigned short*)(ws + 0);         //  4,194,304
    unsigned short* headW_bf  = (unsigned short*)(ws + 4194304);   //  8,196,096
    unsigned short* t0out_bf  = (unsigned short*)(ws + 12390400);  //  8,192,000
    unsigned short* t1out_bf  = (unsigned short*)(ws + 20582400);  //  3,840,000
    unsigned short* projcat   = (unsigned short*)(ws + 24422400);  //    655,360
    float*          h01f      = (float*)(ws + 25077760);           //  2,621,440
    unsigned short* h0_bf     = (unsigned short*)(ws + 27699200);  //  1,048,576
    unsigned short* h1_bf     = (unsigned short*)(ws + 28747776);  //    262,144
    int*   tgt32  = (int*)(ws + 29009920);
    int*   mask32 = (int*)(ws + 29018112);
    float* seH    = (float*)(ws + 29026304);
    float* se0    = (float*)(ws + 29034496);
    float* se1    = (float*)(ws + 29042688);
    float* tgtH   = (float*)(ws + 29050880);
    float* c0     = (float*)(ws + 29059072);
    float* c1     = (float*)(ws + 29067264);
    float* tg0    = (float*)(ws + 29075456);
    float* tg1    = (float*)(ws + 29083648);

    hipMemsetAsync(seH, 0, 3 * N_ROWS * sizeof(float), stream);
    hipMemsetAsync(h01f, 0, 2048 * 320 * sizeof(float), stream);

    preprocess_kernel<<<1, 256, 0, stream>>>(traw, mraw, tgt32, mask32);
    gather_cvt_kernel<<<N_ROWS, 256, 0, stream>>>(lhs, cls, bids, toks, mask32, emb_bf);

    cvt_kernel<<<4002, 256, 0, stream>>>(headW, headW_bf, 4002 * 1024);
    cvt_kernel<<<4000, 256, 0, stream>>>(t0out, t0out_bf, 16000 * 256);
    cvt_kernel<<<1875, 256, 0, stream>>>(t1out, t1out_bf, 30000 * 64);
    cvt_kernel<<<256,  256, 0, stream>>>(t0proj, projcat, 256 * 1024);
    cvt_kernel<<<64,   256, 0, stream>>>(t1proj, projcat + 262144, 64 * 1024);

    // proj GEMM: h01 = emb @ [t0proj;t1proj]^T  (C=320, split-K z=8 x 128)
    gemm_kernel<2><<<dim3(16, 3, 8), 256, 0, stream>>>(
        emb_bf, 1024, projcat, 320, nullptr, h01f, nullptr, 1, 0, 128);
    cvt_h01_kernel<<<2560, 256, 0, stream>>>(h01f, h0_bf, h1_bf);

    // head: C=4002, K=1024, fused sum-exp (bias)
    gemm_kernel<1><<<dim3(16, 32), 256, 0, stream>>>(
        emb_bf, 1024, headW_bf, 4002, headB, nullptr, seH, 1, 0, 1024);
    // tail0 logits: C=16000, K=256, chunk 2
    gemm_kernel<1><<<dim3(16, 63), 256, 0, stream>>>(
        h0_bf, 256, t0out_bf, 16000, nullptr, nullptr, se0, 2, 0, 256);
    // tail1 logits: C=30000, K=64, chunk 4
    gemm_kernel<1><<<dim3(16, 59), 256, 0, stream>>>(
        h1_bf, 64, t1out_bf, 30000, nullptr, nullptr, se1, 4, 0, 64);

    dot_kernel<<<512, 256, 0, stream>>>(emb_bf, headW_bf, headB, h0_bf, t0out_bf,
                                        h1_bf, t1out_bf, tgt32,
                                        tgtH, c0, c1, tg0, tg1);
    finalize_kernel<<<1, 256, 0, stream>>>(seH, se0, se1, tgtH, tg0, tg1,
                                           c0, c1, tgt32, (float*)d_out);
}

// Round 3
// 178.711 us; speedup vs baseline: 5.9649x; 1.1053x over previous
//
#include <hip/hip_runtime.h>
#include <cstdint>
#include <cstddef>

#define N_ROWS 2048
#define D_DIM  1024

typedef __bf16 bf16x8 __attribute__((ext_vector_type(8)));
typedef float  f32x4  __attribute__((ext_vector_type(4)));

__device__ __forceinline__ unsigned short f2bf(float f) {
    unsigned int u = __float_as_uint(f);
    unsigned int r = (u + 0x7fffu + ((u >> 16) & 1u)) >> 16;   // RNE
    return (unsigned short)r;
}
__device__ __forceinline__ float bf2f(unsigned short u) {
    return __uint_as_float(((unsigned int)u) << 16);
}
__device__ __forceinline__ void gload_lds16(const void* g, void* lds) {
    __builtin_amdgcn_global_load_lds(
        (const __attribute__((address_space(1))) unsigned int*)g,
        (__attribute__((address_space(3))) unsigned int*)lds, 16, 0, 0);
}

// ---------------------------------------------------------------------------
// dtype sniffing (targets int32/int64, mask bool/int/float) -> int32 buffers
// ---------------------------------------------------------------------------
__global__ __launch_bounds__(256) void preprocess_kernel(
    const unsigned char* __restrict__ traw,
    const unsigned char* __restrict__ mraw,
    int* __restrict__ tgt32, int* __restrict__ mask32)
{
    __shared__ int fFloat, fByte, fOdd;
    const int tid = threadIdx.x;
    if (tid == 0) { fFloat = 0; fByte = 0; fOdd = 0; }
    __syncthreads();

    const unsigned int* mw = (const unsigned int*)mraw;
    for (int i = tid; i < 512; i += 256) {
        unsigned int w = mw[i];
        if (w == 0x3f800000u) atomicOr(&fFloat, 1);
        if (w & 0xFFFFFF00u)  atomicOr(&fByte, 1);
    }
    const unsigned int* tw = (const unsigned int*)traw;
    for (int i = tid; i < N_ROWS; i += 256) {
        if ((i & 1) && tw[i] != 0u) atomicOr(&fOdd, 1);
    }
    __syncthreads();
    const int mlayout = fFloat ? 2 : (fByte ? 1 : 0);
    const int tis64   = fOdd ? 0 : 1;

    for (int i = tid; i < N_ROWS; i += 256) {
        long long t = tis64 ? ((const long long*)traw)[i] : (long long)((const int*)traw)[i];
        tgt32[i] = (int)t;
        int m;
        if (mlayout == 1) m = (mraw[i] != 0);
        else              m = (((const unsigned int*)mraw)[i] != 0u);
        mask32[i] = m;
    }
}

// ---------------------------------------------------------------------------
// gather + fp32->bf16: emb[n] = replace ? cls[b] : lhs[b,tok]
// ---------------------------------------------------------------------------
__global__ __launch_bounds__(256) void gather_cvt_kernel(
    const float* __restrict__ lhs, const float* __restrict__ cls,
    const int* __restrict__ bids, const int* __restrict__ toks,
    const int* __restrict__ mask32, unsigned short* __restrict__ emb)
{
    const int n = blockIdx.x;
    const int b = bids[n];
    const int tok = toks[n];
    const float* src = mask32[n] ? (cls + (size_t)b * D_DIM)
                                 : (lhs + ((size_t)b * 512 + (size_t)tok) * D_DIM);
    float4 v = ((const float4*)src)[threadIdx.x];
    ushort4 o;
    o.x = f2bf(v.x); o.y = f2bf(v.y); o.z = f2bf(v.z); o.w = f2bf(v.w);
    ((ushort4*)(emb + (size_t)n * D_DIM))[threadIdx.x] = o;
}

// ---------------------------------------------------------------------------
// single fused fp32->bf16 convert of all five weight tensors (vec4 grid-stride)
// ---------------------------------------------------------------------------
__global__ __launch_bounds__(256) void cvt_all_kernel(
    const float* __restrict__ s0, unsigned short* __restrict__ d0,  // headW  4002*1024
    const float* __restrict__ s1, unsigned short* __restrict__ d1,  // t0out 16000*256
    const float* __restrict__ s2, unsigned short* __restrict__ d2,  // t1out 30000*64
    const float* __restrict__ s3, unsigned short* __restrict__ d3,  // t0proj  256*1024
    const float* __restrict__ s4, unsigned short* __restrict__ d4)  // t1proj   64*1024
{
    const int total = 2610432;  // vec4 units
    for (int i = blockIdx.x * 256 + threadIdx.x; i < total; i += gridDim.x * 256) {
        const float* s; unsigned short* d; int off;
        if (i < 1024512)      { s = s0; d = d0; off = i; }
        else if (i < 2048512) { s = s1; d = d1; off = i - 1024512; }
        else if (i < 2528512) { s = s2; d = d2; off = i - 2048512; }
        else if (i < 2594048) { s = s3; d = d3; off = i - 2528512; }
        else                  { s = s4; d = d4; off = i - 2594048; }
        float4 v = ((const float4*)s)[off];
        ushort4 o;
        o.x = f2bf(v.x); o.y = f2bf(v.y); o.z = f2bf(v.z); o.w = f2bf(v.w);
        ((ushort4*)d)[off] = o;
    }
}

// split h01 fp32 [2048][320] -> h0 bf16 [2048][256], h1 bf16 [2048][64]
__global__ __launch_bounds__(256) void cvt_h01_kernel(
    const float* __restrict__ h01, unsigned short* __restrict__ h0,
    unsigned short* __restrict__ h1)
{
    const int idx = blockIdx.x * 256 + threadIdx.x;
    if (idx >= 2048 * 320) return;
    const int r = idx / 320;
    const int c = idx - r * 320;
    const unsigned short v = f2bf(h01[idx]);
    if (c < 256) h0[r * 256 + c] = v;
    else         h1[r * 64 + (c - 256)] = v;
}

// ---------------------------------------------------------------------------
// bf16 MFMA GEMM: C[row][col] = sum_k A[row][k] * W[col][k]
// BM=BN=128, 4 waves (2x2), each wave 64x64 via 4x4 frags of 16x16x32.
// 2-phase double-buffered pipeline carried flat across (colTile, kStep) steps:
//   stage(next) issued BEFORE compute(cur); one __syncthreads (implied vmcnt0)
//   per step. XCD-bijective block swizzle for L2 locality.
// MODE 1: fused sum(exp(logit+bias)) -> atomicAdd(sumexp[row]).
// MODE 2: split-K (grid.z), atomicAdd fp32 into outF.
// LDS XOR swizzle: 16B slot s of row r stored at s ^ ((r>>1)&3); staged via
// pre-swizzled global source + linear LDS dest (G21).
// ---------------------------------------------------------------------------
template<int MODE>
__global__ __launch_bounds__(256) void gemm_kernel(
    const unsigned short* __restrict__ A, int K,
    const unsigned short* __restrict__ W, int C,
    const float* __restrict__ bias,
    float* __restrict__ outF,
    float* __restrict__ sumexp,
    int colTiles, int kLen)
{
    __shared__ char lds[32768];   // A: [2][8192] @0, W: [2][8192] @16384

    // bijective XCD swizzle (m204): consecutive new ids land on one XCD
    const int gx = gridDim.x, gy = gridDim.y;
    const int nwg = gx * gy * gridDim.z;
    const int lid = blockIdx.x + gx * (blockIdx.y + gy * blockIdx.z);
    const int xcd = lid & 7, idx8 = lid >> 3;
    const int qq = nwg >> 3, rr = nwg & 7;
    const int wg = (xcd < rr ? xcd * (qq + 1) : rr * (qq + 1) + (xcd - rr) * qq) + idx8;
    const int bx = wg % gx;
    const int t1 = wg / gx;
    const int by = t1 % gy;
    const int bz = t1 / gy;

    const int tid = threadIdx.x;
    const int w  = tid >> 6;
    const int l  = tid & 63;
    const int wr = w >> 1, wc = w & 1;
    const int q16 = l >> 4, r16 = l & 15;
    const int rowA0 = bx * 128;
    const int kBeg  = bz * kLen;

    const int sRl = (w << 5) + (l >> 2);
    const int sS  = l & 3;

    const int nt    = kLen >> 5;
    const int total = colTiles * nt;

    float esum[4][4];
    if (MODE == 1) {
        #pragma unroll
        for (int m = 0; m < 4; ++m)
            #pragma unroll
            for (int r = 0; r < 4; ++r) esum[m][r] = 0.f;
    }

    auto stage = [&](int ct, int kt, int buf) {
        const int k0 = kBeg + (kt << 5);
        const int cB = (by * colTiles + ct) * 128;
        char* Ab = lds + (buf << 13);
        char* Wb = lds + 16384 + (buf << 13);
        #pragma unroll
        for (int it = 0; it < 2; ++it) {
            const int R  = sRl + (it << 4);
            const int Sp = sS ^ ((R >> 1) & 3);
            gload_lds16(A + (size_t)(rowA0 + R) * K + k0 + Sp * 8,
                        Ab + (w << 11) + (it << 10));
            int Rw = cB + R; if (Rw >= C) Rw = C - 1;
            gload_lds16(W + (size_t)Rw * K + k0 + Sp * 8,
                        Wb + (w << 11) + (it << 10));
        }
    };

    f32x4 acc[4][4];

    stage(0, 0, 0);
    __syncthreads();                       // implied vmcnt(0) drains prologue

    int kt = 0, ct = 0;                    // compute coords
    int kn = 1, cn = 0;                    // next-stage coords
    if (kn == nt) { kn = 0; cn = 1; }

    for (int step = 0; step < total; ++step) {
        const int buf = step & 1;
        if (step + 1 < total) {
            stage(cn, kn, buf ^ 1);        // loads fly during compute below
            if (++kn == nt) { kn = 0; ++cn; }
        }

        if (kt == 0) {
            #pragma unroll
            for (int m = 0; m < 4; ++m)
                #pragma unroll
                for (int n = 0; n < 4; ++n) acc[m][n] = (f32x4){0.f, 0.f, 0.f, 0.f};
        }

        char* Ab = lds + (buf << 13);
        char* Wb = lds + 16384 + (buf << 13);
        bf16x8 af[4], bfr[4];
        #pragma unroll
        for (int m = 0; m < 4; ++m) {
            const int row = (wr << 6) + (m << 4) + r16;
            af[m] = *reinterpret_cast<const bf16x8*>(
                Ab + row * 64 + ((q16 ^ ((row >> 1) & 3)) << 4));
        }
        #pragma unroll
        for (int n = 0; n < 4; ++n) {
            const int row = (wc << 6) + (n << 4) + r16;
            bfr[n] = *reinterpret_cast<const bf16x8*>(
                Wb + row * 64 + ((q16 ^ ((row >> 1) & 3)) << 4));
        }
        #pragma unroll
        for (int m = 0; m < 4; ++m)
            #pragma unroll
            for (int n = 0; n < 4; ++n)
                acc[m][n] = __builtin_amdgcn_mfma_f32_16x16x32_bf16(
                    af[m], bfr[n], acc[m][n], 0, 0, 0);

        if (kt == nt - 1) {
            const int cB = (by * colTiles + ct) * 128;
            if (MODE == 2) {
                #pragma unroll
                for (int n = 0; n < 4; ++n) {
                    const int c = cB + (wc << 6) + (n << 4) + r16;
                    if (c < C) {
                        #pragma unroll
                        for (int m = 0; m < 4; ++m)
                            #pragma unroll
                            for (int r = 0; r < 4; ++r) {
                                const int row = rowA0 + (wr << 6) + (m << 4) + (q16 << 2) + r;
                                atomicAdd(&outF[(size_t)row * C + c], acc[m][n][r]);
                            }
                    }
                }
            } else {
                float bj[4]; bool vj[4];
                #pragma unroll
                for (int n = 0; n < 4; ++n) {
                    const int c = cB + (wc << 6) + (n << 4) + r16;
                    vj[n] = (c < C);
                    bj[n] = (vj[n] && bias) ? bias[c] : 0.f;
                }
                #pragma unroll
                for (int m = 0; m < 4; ++m)
                    #pragma unroll
                    for (int r = 0; r < 4; ++r) {
                        float s = 0.f;
                        #pragma unroll
                        for (int n = 0; n < 4; ++n)
                            if (vj[n]) s += __expf(acc[m][n][r] + bj[n]);
                        esum[m][r] += s;
                    }
            }
        }

        __syncthreads();                   // drains next-stage loads (vmcnt0)
        if (++kt == nt) { kt = 0; ++ct; }
    }

    if (MODE == 1) {
        #pragma unroll
        for (int m = 0; m < 4; ++m)
            #pragma unroll
            for (int r = 0; r < 4; ++r) {
                float v = esum[m][r];
                v += __shfl_xor(v, 1); v += __shfl_xor(v, 2);
                v += __shfl_xor(v, 4); v += __shfl_xor(v, 8);
                if (r16 == 0)
                    atomicAdd(&sumexp[rowA0 + (wr << 6) + (m << 4) + (q16 << 2) + r], v);
            }
    }
}

// ---------------------------------------------------------------------------
// per-row target / cluster logit dots (one wave per row)
// ---------------------------------------------------------------------------
__global__ __launch_bounds__(256) void dot_kernel(
    const unsigned short* __restrict__ emb,
    const unsigned short* __restrict__ headW,
    const float* __restrict__ headB,
    const unsigned short* __restrict__ h0,
    const unsigned short* __restrict__ t0out,
    const unsigned short* __restrict__ h1,
    const unsigned short* __restrict__ t1out,
    const int* __restrict__ tgt32,
    float* __restrict__ tgtH, float* __restrict__ c0, float* __restrict__ c1,
    float* __restrict__ tg0, float* __restrict__ tg1)
{
    const int n = blockIdx.x * 4 + (threadIdx.x >> 6);
    const int l = threadIdx.x & 63;
    const int t = tgt32[n];

    const unsigned short* e  = emb + (size_t)n * 1024;
    const int hrow = (t < 4000) ? t : 0;
    const unsigned short* wt = headW + (size_t)hrow * 1024;
    const unsigned short* w0 = headW + (size_t)4000 * 1024;
    const unsigned short* w1 = headW + (size_t)4001 * 1024;

    float st = 0.f, s0 = 0.f, s1 = 0.f;
    for (int i = l; i < 1024; i += 64) {
        const float ev = bf2f(e[i]);
        st += ev * bf2f(wt[i]);
        s0 += ev * bf2f(w0[i]);
        s1 += ev * bf2f(w1[i]);
    }
    float stail = 0.f;
    if (t >= 4000 && t < 20000) {
        const unsigned short* h  = h0 + (size_t)n * 256;
        const unsigned short* ww = t0out + (size_t)(t - 4000) * 256;
        for (int i = l; i < 256; i += 64) stail += bf2f(h[i]) * bf2f(ww[i]);
    } else if (t >= 20000) {
        const unsigned short* h  = h1 + (size_t)n * 64;
        const unsigned short* ww = t1out + (size_t)(t - 20000) * 64;
        stail = bf2f(h[l]) * bf2f(ww[l]);
    }
    #pragma unroll
    for (int msk = 1; msk < 64; msk <<= 1) {
        st    += __shfl_xor(st, msk);
        s0    += __shfl_xor(s0, msk);
        s1    += __shfl_xor(s1, msk);
        stail += __shfl_xor(stail, msk);
    }
    if (l == 0) {
        c0[n] = s0 + headB[4000];
        c1[n] = s1 + headB[4001];
        if (t < 4000)       tgtH[n] = st + headB[t];
        else if (t < 20000) tg0[n]  = stail;
        else                tg1[n]  = stail;
    }
}

// ---------------------------------------------------------------------------
__global__ __launch_bounds__(256) void finalize_kernel(
    const float* __restrict__ seH, const float* __restrict__ se0,
    const float* __restrict__ se1,
    const float* __restrict__ tgtH, const float* __restrict__ tg0,
    const float* __restrict__ tg1,
    const float* __restrict__ c0, const float* __restrict__ c1,
    const int* __restrict__ tgt32,
    float* __restrict__ out)
{
    const int tid = threadIdx.x;
    float lsum = 0.f;
    for (int n = tid; n < N_ROWS; n += 256) {
        const float lseH = logf(seH[n]);
        const int t = tgt32[n];
        float o;
        if (t < 4000)        o = tgtH[n] - lseH;
        else if (t < 20000)  o = (c0[n] - lseH) + tg0[n] - logf(se0[n]);
        else                 o = (c1[n] - lseH) + tg1[n] - logf(se1[n]);
        out[n] = o;
        lsum += o;
    }
    #pragma unroll
    for (int m = 1; m < 64; m <<= 1) lsum += __shfl_xor(lsum, m);
    __shared__ float wsum[4];
    const int wid = tid >> 6;
    if ((tid & 63) == 0) wsum[wid] = lsum;
    __syncthreads();
    if (tid == 0) out[N_ROWS] = -(wsum[0] + wsum[1] + wsum[2] + wsum[3]) / (float)N_ROWS;
}

// ---------------------------------------------------------------------------
extern "C" void kernel_launch(void* const* d_in, const int* in_sizes, int n_in,
                              void* d_out, int out_size, void* d_ws, size_t ws_size,
                              hipStream_t stream)
{
    const unsigned char* traw = (const unsigned char*)d_in[0];
    const float* lhs    = (const float*)d_in[1];
    const float* cls    = (const float*)d_in[2];
    const int*   bids   = (const int*)d_in[3];
    const int*   toks   = (const int*)d_in[4];
    const unsigned char* mraw = (const unsigned char*)d_in[5];
    const float* headW  = (const float*)d_in[6];
    const float* headB  = (const float*)d_in[7];
    const float* t0proj = (const float*)d_in[8];
    const float* t0out  = (const float*)d_in[9];
    const float* t1proj = (const float*)d_in[10];
    const float* t1out  = (const float*)d_in[11];

    char* ws = (char*)d_ws;
    unsigned short* emb_bf    = (unsigned short*)(ws + 0);         //  4,194,304
    unsigned short* headW_bf  = (unsigned short*)(ws + 4194304);   //  8,196,096
    unsigned short* t0out_bf  = (unsigned short*)(ws + 12390400);  //  8,192,000
    unsigned short* t1out_bf  = (unsigned short*)(ws + 20582400);  //  3,840,000
    unsigned short* projcat   = (unsigned short*)(ws + 24422400);  //    655,360
    float*          h01f      = (float*)(ws + 25077760);           //  2,621,440
    unsigned short* h0_bf     = (unsigned short*)(ws + 27699200);  //  1,048,576
    unsigned short* h1_bf     = (unsigned short*)(ws + 28747776);  //    262,144
    int*   tgt32  = (int*)(ws + 29009920);
    int*   mask32 = (int*)(ws + 29018112);
    float* seH    = (float*)(ws + 29026304);
    float* se0    = (float*)(ws + 29034496);
    float* se1    = (float*)(ws + 29042688);
    float* tgtH   = (float*)(ws + 29050880);
    float* c0     = (float*)(ws + 29059072);
    float* c1     = (float*)(ws + 29067264);
    float* tg0    = (float*)(ws + 29075456);
    float* tg1    = (float*)(ws + 29083648);

    hipMemsetAsync(seH, 0, 3 * N_ROWS * sizeof(float), stream);
    hipMemsetAsync(h01f, 0, 2048 * 320 * sizeof(float), stream);

    preprocess_kernel<<<1, 256, 0, stream>>>(traw, mraw, tgt32, mask32);
    gather_cvt_kernel<<<N_ROWS, 256, 0, stream>>>(lhs, cls, bids, toks, mask32, emb_bf);

    cvt_all_kernel<<<2048, 256, 0, stream>>>(headW, headW_bf, t0out, t0out_bf,
                                             t1out, t1out_bf, t0proj, projcat,
                                             t1proj, projcat + 262144);

    // proj GEMM: h01 = emb @ [t0proj;t1proj]^T  (C=320, split-K z=8 x 128)
    gemm_kernel<2><<<dim3(16, 3, 8), 256, 0, stream>>>(
        emb_bf, 1024, projcat, 320, nullptr, h01f, nullptr, 1, 128);
    cvt_h01_kernel<<<2560, 256, 0, stream>>>(h01f, h0_bf, h1_bf);

    // head: C=4002, K=1024, fused sum-exp (bias)
    gemm_kernel<1><<<dim3(16, 32), 256, 0, stream>>>(
        emb_bf, 1024, headW_bf, 4002, headB, nullptr, seH, 1, 1024);
    // tail0 logits: C=16000, K=256, chunk 2
    gemm_kernel<1><<<dim3(16, 63), 256, 0, stream>>>(
        h0_bf, 256, t0out_bf, 16000, nullptr, nullptr, se0, 2, 256);
    // tail1 logits: C=30000, K=64, chunk 4
    gemm_kernel<1><<<dim3(16, 59), 256, 0, stream>>>(
        h1_bf, 64, t1out_bf, 30000, nullptr, nullptr, se1, 4, 64);

    dot_kernel<<<512, 256, 0, stream>>>(emb_bf, headW_bf, headB, h0_bf, t0out_bf,
                                        h1_bf, t1out_bf, tgt32,
                                        tgtH, c0, c1, tg0, tg1);
    finalize_kernel<<<1, 256, 0, stream>>>(seH, se0, se1, tgtH, tg0, tg1,
                                           c0, c1, tgt32, (float*)d_out);
}